// Round 3
// baseline (485.542 us; speedup 1.0000x reference)
//
#include <hip/hip_runtime.h>

#define N_NEURONS   100000
#define INPUT_SIZE  1024
#define OUTPUT_SIZE 256
#define E_SYN       10000000
#define STEPS       3

#define NR          8              // dst ranges
#define NS          8              // src sub-ranges per dst range
#define NCAT        (NR * NS)      // 64 buckets
#define BIN         12500          // neurons per range; NR*BIN == N_NEURONS
#define SCAT_BLK    1024
#define CSTRIPE     32             // scatter blocks per dst range (8*32 = 256 = 1/CU)
#define RG          8              // reduce groups (fixed association)
#define RSL         (CSTRIPE / RG) // 4 slabs per group
#define CAP         1280000        // per-range capacity (mean 1.25M + pad slack)
#define VEC4        (E_SYN / 4)

// partition pipeline geometry (one wave per chunk)
#define CHK         2048
#define NCH         4883               // ceil(E_SYN / CHK)
#define PITER       (CHK / 256)        // 8 int4 iterations per wave
#define HP_GRID     ((NCH + 3) / 4)    // 4 waves per 256-thr block
#define SCJ         5                  // scan items per thread (1024*5 >= NCH)

// v init
__global__ void init_state(const float* __restrict__ x, float* __restrict__ v) {
    int i = blockIdx.x * blockDim.x + threadIdx.x;
    if (i < N_NEURONS) v[i] = (i < INPUT_SIZE) ? x[i] : 0.0f;
}

// Per-chunk 64-category histogram via per-wave LDS counters (no ballots).
__global__ __launch_bounds__(256) void hist_kernel(const int* __restrict__ src,
                                                   const int* __restrict__ dst,
                                                   int* __restrict__ hist) {
    __shared__ int h[4][NCAT];
    const int lane  = threadIdx.x & 63;
    const int wv    = threadIdx.x >> 6;
    const int chunk = blockIdx.x * 4 + wv;
    if (chunk >= NCH) return;
    h[wv][lane] = 0;
    const int beg = chunk * CHK;
    const int4* dst4 = (const int4*)dst;
    const int4* src4 = (const int4*)src;
    for (int it = 0; it < PITER; ++it) {
        int e = beg + (it * 64 + lane) * 4;
        if (e < E_SYN) {
            int4 d4 = dst4[e >> 2];
            int4 s4 = src4[e >> 2];
            atomicAdd(&h[wv][(d4.x / BIN) * NS + s4.x / BIN], 1);
            atomicAdd(&h[wv][(d4.y / BIN) * NS + s4.y / BIN], 1);
            atomicAdd(&h[wv][(d4.z / BIN) * NS + s4.z / BIN], 1);
            atomicAdd(&h[wv][(d4.w / BIN) * NS + s4.w / BIN], 1);
        }
    }
    hist[(size_t)lane * NCH + chunk] = h[wv][lane];
}

// Per-cat exclusive scan over chunk counts -> relative bases + totals.
__global__ __launch_bounds__(1024) void scan_kernel(const int* __restrict__ hist,
                                                    int* __restrict__ bases,
                                                    int* __restrict__ gtot) {
    const int ct = blockIdx.x;
    const int t = threadIdx.x;
    const int lane = t & 63;
    const int wv   = t >> 6;
    int vals[SCJ];
    int s = 0;
#pragma unroll
    for (int j = 0; j < SCJ; ++j) {
        int idx = t * SCJ + j;
        int vv  = (idx < NCH) ? hist[(size_t)ct * NCH + idx] : 0;
        vals[j] = vv;
        s += vv;
    }
    int x = s;
#pragma unroll
    for (int d = 1; d < 64; d <<= 1) {
        int y = __shfl_up(x, d, 64);
        if (lane >= d) x += y;
    }
    __shared__ int wsum[16];
    if (lane == 63) wsum[wv] = x;
    __syncthreads();
    if (wv == 0) {
        int y = (lane < 16) ? wsum[lane] : 0;
        int z = y;
#pragma unroll
        for (int d = 1; d < 16; d <<= 1) {
            int u = __shfl_up(z, d, 64);
            if (lane >= d) z += u;
        }
        if (lane < 16) wsum[lane] = z - y;
    }
    __syncthreads();
    int run = (x - s) + wsum[wv];
#pragma unroll
    for (int j = 0; j < SCJ; ++j) {
        int idx = t * SCJ + j;
        if (idx < NCH) bases[(size_t)ct * NCH + idx] = run;
        run += vals[j];
    }
    if (t == 1023) gtot[ct] = run;
}

// Absolute cat starts: range-major, each cat start rounded up to even
// (16B-aligned int4 pair streaming in scatter).
__global__ void compose_kernel(const int* __restrict__ gtot, int* __restrict__ gstart) {
    int r = threadIdx.x;
    if (r < NR) {
        int s = r * CAP;
        for (int sb = 0; sb < NS; ++sb) {
            int c = r * NS + sb;
            gstart[c] = s;
            s = (s + gtot[c] + 1) & ~1;
        }
    }
}

// Partition into 64 (dst-range, src-subrange) buckets of packed 8B records.
// Per-wave LDS cursors: pos = atomicAdd(&cur[wv][cat],1) replaces the whole
// ballot/rank machinery (~16 VALU/step). Same-cat lanes in a step still get
// consecutive pos -> coalescer merges runs. Record keeps FULL src (17b)<<14 |
// dst_local (14b) so downstream indexing is unchanged.
__global__ __launch_bounds__(256) void partition_kernel(
        const float* __restrict__ w,
        const int*   __restrict__ src,
        const int*   __restrict__ dst,
        const int*   __restrict__ bases,
        const int*   __restrict__ gstart,
        int2* __restrict__ recs) {
    __shared__ int cur[4][NCAT];
    const int lane  = threadIdx.x & 63;
    const int wv    = threadIdx.x >> 6;
    const int chunk = blockIdx.x * 4 + wv;
    if (chunk >= NCH) return;
    cur[wv][lane] = gstart[lane] + bases[(size_t)lane * NCH + chunk];
    const int beg = chunk * CHK;
    const int4* dst4 = (const int4*)dst;
    const int4* src4 = (const int4*)src;
    const int4* wq4  = (const int4*)w;
    for (int it = 0; it < PITER; ++it) {
        int e = beg + (it * 64 + lane) * 4;
        if (e < E_SYN) {
            int4 d4 = dst4[e >> 2];
            int4 s4 = src4[e >> 2];
            int4 q4 = wq4[e >> 2];
            int dd[4] = {d4.x, d4.y, d4.z, d4.w};
            int ss[4] = {s4.x, s4.y, s4.z, s4.w};
            int qq[4] = {q4.x, q4.y, q4.z, q4.w};
#pragma unroll
            for (int k = 0; k < 4; ++k) {
                int d = dd[k], s = ss[k];
                int r = d / BIN;
                int cat = r * NS + s / BIN;
                int pos = atomicAdd(&cur[wv][cat], 1);
                recs[(size_t)pos] = make_int2((s << 14) | (d - r * BIN), qq[k]);
            }
        }
    }
}

// Per step: block (r,c) iterates the 8 src-subranges of dst-range r. Per
// phase: stage the 50KB v-slice into LDS, then stream the sub-bucket stripe;
// gather AND accumulate are both LDS ops (no global random access at all).
// 100KB dynamic LDS -> 1 block/CU, grid 256 = 1/CU.
__global__ __launch_bounds__(SCAT_BLK) void scatter_sorted2(
        const int2* __restrict__ recs,
        const int*  __restrict__ gstart,
        const int*  __restrict__ gtot,
        const float* __restrict__ v,
        float* __restrict__ partials) {
    extern __shared__ float smem[];
    float* bins = smem;            // [BIN]
    float* vst  = smem + BIN;      // [BIN]
    const int r = blockIdx.x / CSTRIPE;
    const int c = blockIdx.x % CSTRIPE;
    const int tid = threadIdx.x;
    for (int j = tid; j < BIN; j += SCAT_BLK) bins[j] = 0.0f;
    const int stride = CSTRIPE * SCAT_BLK;
    for (int sb = 0; sb < NS; ++sb) {
        __syncthreads();                       // prior phase done before vst overwrite
        const float4* vs4 = (const float4*)(v + (size_t)sb * BIN);
        float4* vt4 = (float4*)vst;
#pragma unroll 4
        for (int j = tid; j < BIN / 4; j += SCAT_BLK) vt4[j] = vs4[j];
        __syncthreads();
        const int start = gstart[r * NS + sb];
        const int T     = gtot[r * NS + sb];
        const int P     = T >> 1;
        const int sbb   = sb * BIN;
        const int4* base4 = (const int4*)(recs + (size_t)start);
        // 3-deep explicit loads for HBM MLP despite thin phases
        int u0 = c * SCAT_BLK + tid;
        int u1 = u0 + stride;
        int u2 = u1 + stride;
        bool k0 = u0 < P, k1 = u1 < P, k2 = u2 < P;
        int4 a0, a1, a2;
        if (k0) a0 = base4[u0];
        if (k1) a1 = base4[u1];
        if (k2) a2 = base4[u2];
        if (k0) {
            atomicAdd(&bins[a0.x & 16383], vst[(a0.x >> 14) - sbb] * __int_as_float(a0.y));
            atomicAdd(&bins[a0.z & 16383], vst[(a0.z >> 14) - sbb] * __int_as_float(a0.w));
        }
        if (k1) {
            atomicAdd(&bins[a1.x & 16383], vst[(a1.x >> 14) - sbb] * __int_as_float(a1.y));
            atomicAdd(&bins[a1.z & 16383], vst[(a1.z >> 14) - sbb] * __int_as_float(a1.w));
        }
        if (k2) {
            atomicAdd(&bins[a2.x & 16383], vst[(a2.x >> 14) - sbb] * __int_as_float(a2.y));
            atomicAdd(&bins[a2.z & 16383], vst[(a2.z >> 14) - sbb] * __int_as_float(a2.w));
        }
        for (int u = u2 + stride; u < P; u += stride) {
            int4 a = base4[u];
            atomicAdd(&bins[a.x & 16383], vst[(a.x >> 14) - sbb] * __int_as_float(a.y));
            atomicAdd(&bins[a.z & 16383], vst[(a.z >> 14) - sbb] * __int_as_float(a.w));
        }
        if ((T & 1) && c == 0 && tid == 0) {
            int2 p = recs[(size_t)start + T - 1];
            atomicAdd(&bins[p.x & 16383], vst[(p.x >> 14) - sbb] * __int_as_float(p.y));
        }
    }
    __syncthreads();
    float* o = partials + (size_t)(r * CSTRIPE + c) * BIN;
    for (int j = tid; j < BIN; j += SCAT_BLK) o[j] = bins[j];
}

// Fused reduce: 32 slabs as 8 sequential groups of 4 (fixed association),
// then bias + tanh (except outputs).
__global__ void reduce_fused(const float* __restrict__ partials,
                             const float* __restrict__ bias,
                             float* __restrict__ v,
                             float* __restrict__ out,
                             int write_out) {
    int i4 = 4 * (blockIdx.x * blockDim.x + threadIdx.x);
    if (i4 >= N_NEURONS) return;
    const int r = i4 / BIN;
    const int j = i4 - r * BIN;
    const float* base = partials + (size_t)(r * CSTRIPE) * BIN + j;
    float4 tot = {0.f, 0.f, 0.f, 0.f};
#pragma unroll 2
    for (int g = 0; g < RG; ++g) {
        float4 a = {0.f, 0.f, 0.f, 0.f};
#pragma unroll
        for (int cc = 0; cc < RSL; ++cc) {
            float4 p = *(const float4*)(base + (size_t)(g * RSL + cc) * BIN);
            a.x += p.x; a.y += p.y; a.z += p.z; a.w += p.w;
        }
        tot.x += a.x; tot.y += a.y; tot.z += a.z; tot.w += a.w;
    }
    float av[4] = {tot.x, tot.y, tot.z, tot.w};
#pragma unroll
    for (int k = 0; k < 4; ++k) {
        int i = i4 + k;
        float val = av[k] + ((i >= INPUT_SIZE) ? bias[i - INPUT_SIZE] : 0.0f);
        float nv  = (i < N_NEURONS - OUTPUT_SIZE) ? tanhf(val) : val;
        v[i] = nv;
        if (write_out && i >= N_NEURONS - OUTPUT_SIZE)
            out[i - (N_NEURONS - OUTPUT_SIZE)] = val;
    }
}

// ---- fallback (small ws): multi-pass binned rescan path ----
__global__ void scatter_binned(const float* __restrict__ w,
                               const int*   __restrict__ src,
                               const int*   __restrict__ dst,
                               const float* __restrict__ v,
                               float*       __restrict__ partials,
                               int C) {
    __shared__ float bins[BIN];
    const int r = blockIdx.x / C;
    const int c = blockIdx.x % C;
    const int lo = r * BIN;
    const int hi = lo + BIN;
    for (int j = threadIdx.x; j < BIN; j += blockDim.x) bins[j] = 0.0f;
    __syncthreads();
    const int4*   src4 = (const int4*)src;
    const int4*   dst4 = (const int4*)dst;
    const float4* w4v  = (const float4*)w;
    const int stride = C * blockDim.x;
    for (int u = c * blockDim.x + threadIdx.x; u < VEC4; u += stride) {
        const int4   s4 = src4[u];
        const int4   d4 = dst4[u];
        const float4 wv = w4v[u];
        int   s[4] = {s4.x, s4.y, s4.z, s4.w};
        int   d[4] = {d4.x, d4.y, d4.z, d4.w};
        float ww[4] = {wv.x, wv.y, wv.z, wv.w};
#pragma unroll
        for (int k = 0; k < 4; ++k)
            if (d[k] >= lo && d[k] < hi)
                atomicAdd(&bins[d[k] - lo], v[s[k]] * ww[k]);
    }
    __syncthreads();
    float* o = partials + ((size_t)(r * C + c)) * BIN;
    for (int j = threadIdx.x; j < BIN; j += blockDim.x) o[j] = bins[j];
}
__global__ void reduce_update_fb(const float* __restrict__ partials,
                                 const float* __restrict__ bias,
                                 float* __restrict__ v,
                                 float* __restrict__ out,
                                 int C, int write_out) {
    int i4 = 4 * (blockIdx.x * blockDim.x + threadIdx.x);
    if (i4 >= N_NEURONS) return;
    const int r = i4 / BIN;
    const int j = i4 - r * BIN;
    const float* base = partials + ((size_t)r * C) * BIN + j;
    float4 acc = {0.f, 0.f, 0.f, 0.f};
    for (int c = 0; c < C; ++c) {
        float4 p = *(const float4*)(base + (size_t)c * BIN);
        acc.x += p.x; acc.y += p.y; acc.z += p.z; acc.w += p.w;
    }
    float av[4] = {acc.x, acc.y, acc.z, acc.w};
#pragma unroll
    for (int k = 0; k < 4; ++k) {
        int i = i4 + k;
        float val = av[k] + ((i >= INPUT_SIZE) ? bias[i - INPUT_SIZE] : 0.0f);
        float nv  = (i < N_NEURONS - OUTPUT_SIZE) ? tanhf(val) : val;
        v[i] = nv;
        if (write_out && i >= N_NEURONS - OUTPUT_SIZE)
            out[i - (N_NEURONS - OUTPUT_SIZE)] = val;
    }
}

extern "C" void kernel_launch(void* const* d_in, const int* in_sizes, int n_in,
                              void* d_out, int out_size, void* d_ws, size_t ws_size,
                              hipStream_t stream) {
    const float* x    = (const float*)d_in[0];
    const float* w    = (const float*)d_in[1];
    const float* bias = (const float*)d_in[2];
    const int*   src  = (const int*)d_in[3];
    const int*   dst  = (const int*)d_in[4];
    float* out = (float*)d_out;

    const int blk = 256;
    const int grid_n   = (N_NEURONS + blk - 1) / blk;
    const int red_grid = (N_NEURONS / 4 + blk - 1) / blk;

    // sorted-path ws layout: v | partials | hist | bases | recs | gtot | gstart
    float* v        = (float*)d_ws;
    float* partials = v + N_NEURONS;
    int*   hist     = (int*)(partials + (size_t)NR * CSTRIPE * BIN);
    int*   bases    = hist + (size_t)NCAT * NCH;
    int2*  recs     = (int2*)(bases + (size_t)NCAT * NCH);
    int*   gtot     = (int*)(recs + (size_t)NR * CAP);
    int*   gstart   = gtot + NCAT;
    size_t need = (size_t)((char*)(gstart + NCAT) - (char*)d_ws);

    if (ws_size >= need) {
        static int attr_set = 0;
        if (!attr_set) {
            hipFuncSetAttribute((const void*)scatter_sorted2,
                                hipFuncAttributeMaxDynamicSharedMemorySize,
                                2 * BIN * (int)sizeof(float));
            attr_set = 1;
        }
        init_state<<<grid_n, blk, 0, stream>>>(x, v);
        hist_kernel<<<HP_GRID, 256, 0, stream>>>(src, dst, hist);
        scan_kernel<<<NCAT, 1024, 0, stream>>>(hist, bases, gtot);
        compose_kernel<<<1, 64, 0, stream>>>(gtot, gstart);
        partition_kernel<<<HP_GRID, 256, 0, stream>>>(w, src, dst, bases, gstart, recs);
        for (int s = 0; s < STEPS; ++s) {
            scatter_sorted2<<<NR * CSTRIPE, SCAT_BLK, 2 * BIN * sizeof(float), stream>>>(
                recs, gstart, gtot, v, partials);
            reduce_fused<<<red_grid, blk, 0, stream>>>(
                partials, bias, v, out, s == STEPS - 1 ? 1 : 0);
        }
    } else {
        long C = (long)(ws_size / 4 / N_NEURONS) - 1;
        if (C > 64) C = 64;
        if (C < 1) C = 1;
        float* part_fb = v + N_NEURONS;
        init_state<<<grid_n, blk, 0, stream>>>(x, v);
        for (int s = 0; s < STEPS; ++s) {
            scatter_binned<<<NR * (int)C, SCAT_BLK, 0, stream>>>(
                w, src, dst, v, part_fb, (int)C);
            reduce_update_fb<<<red_grid, blk, 0, stream>>>(
                part_fb, bias, v, out, (int)C, s == STEPS - 1 ? 1 : 0);
        }
    }
}